// Round 11
// baseline (169.337 us; speedup 1.0000x reference)
//
#include <hip/hip_runtime.h>
#include <math.h>

namespace {

constexpr int Bb = 16;
constexpr int Ll = 1024;
constexpr int Dd = 512;
constexpr int TOPK = 6;
constexpr int Kc = 512;

typedef short  short8 __attribute__((ext_vector_type(8)));
typedef float  f32x4  __attribute__((ext_vector_type(4)));

__device__ __forceinline__ short f2bf(float x) {
  unsigned u = __builtin_bit_cast(unsigned, x);
  u += 0x7fffu + ((u >> 16) & 1u);          // RNE
  return (short)(u >> 16);
}
__device__ __forceinline__ float bf2f(short b) {
  unsigned u = ((unsigned)(unsigned short)b) << 16;
  return __builtin_bit_cast(float, u);
}
__device__ __forceinline__ void g2l16(const void* g, void* l) {
  __builtin_amdgcn_global_load_lds(
      (const __attribute__((address_space(1))) unsigned*)g,
      (__attribute__((address_space(3))) unsigned*)l, 16, 0, 0);
}
__device__ __forceinline__ short8 cvt8(float4 a, float4 b) {
  short8 o;
  o[0] = f2bf(a.x); o[1] = f2bf(a.y); o[2] = f2bf(a.z); o[3] = f2bf(a.w);
  o[4] = f2bf(b.x); o[5] = f2bf(b.y); o[6] = f2bf(b.z); o[7] = f2bf(b.w);
  return o;
}

#define BARRIER() do { asm volatile("" ::: "memory"); \
    __builtin_amdgcn_s_barrier(); \
    asm volatile("" ::: "memory"); } while (0)
#define VMCNT8() asm volatile("s_waitcnt vmcnt(8)" ::: "memory")
#define VMCNT4() asm volatile("s_waitcnt vmcnt(4)" ::: "memory")
#define VMCNT0() asm volatile("s_waitcnt vmcnt(0)" ::: "memory")
#define LGKM0()  do { asm volatile("s_waitcnt lgkmcnt(0)" ::: "memory"); \
    __builtin_amdgcn_sched_barrier(0); } while (0)

// ===========================================================================
// r7's g64, modes 0/1 (refcheck'd; front ~40 us = best measured):
// NT GEMM, 128x128 tile, BK=64 (8 K-steps), 256 thr (4 waves, 2m x 2n of
// 64x64), depth-2 LDS ring, counted entry-vmcnt, XOR-swizzled LDS.
// MODE 0: tiny — A,B bf16; C bf16.   z: 0 = Gt, 1 = Ht       (32 blocks)
// MODE 1: front — A fp32 (T14 split-stage + cvt), B bf16; C bf16.
//         z: 0 = T = Q@Gt^T, 1 = U = V@Ht^T                  (512 x 2 blocks)
// ===========================================================================
template<int MODE>
__global__ __launch_bounds__(256) void g64(
    const void* __restrict__ A0, const void* __restrict__ A1,
    const short* __restrict__ B0, const short* __restrict__ B1,
    void* __restrict__ C0, void* __restrict__ C1)
{
  __shared__ short lds[2][16384];   // per buf: A [0,8192), B [8192,16384)

  const int tid = threadIdx.x;
  int z, m0, n0;
  if (MODE == 0) {
    z = blockIdx.x >> 4;
    const int s = blockIdx.x & 15;
    m0 = (s >> 2) * 128;  n0 = (s & 3) * 128;
  } else {
    z = blockIdx.z;
    const int fb = blockIdx.x;                 // 512, XCD chunk = 64
    const int s  = (fb & 7) * 64 + (fb >> 3);
    m0 = (s >> 2) * 128;  n0 = (s & 3) * 128;
  }

  const int rS  = tid >> 3;                    // 0..31
  const int c8S = (tid & 7) ^ (rS & 7);        // swizzled source 16B-slot
  const short* Ga = nullptr;  const float* Fa = nullptr;
  const short* Gb = nullptr;
  if (MODE == 0) {
    Ga = (const short*)(z ? A1 : A0) + (size_t)(m0 + rS) * Kc + c8S * 8;
    Gb = (z ? B1 : B0) + (size_t)(n0 + rS) * Kc + c8S * 8;
  } else {
    Fa = (const float*)(z ? A1 : A0) + (size_t)(m0 + rS) * Kc + c8S * 8;
    Gb = (z ? B1 : B0) + (size_t)(n0 + rS) * Kc + c8S * 8;
  }

  const int lane = tid & 63;
  const int wid  = tid >> 6;
  const int wr = wid >> 1, wn = wid & 1;
  const int lo = lane & 15, hi = lane >> 4;
  int aoff[2][4], boff[2][4];
#pragma unroll
  for (int i = 0; i < 4; ++i) {
    const int ar = wr * 64 + i * 16 + lo;
    const int br = wn * 64 + i * 16 + lo;
#pragma unroll
    for (int ks = 0; ks < 2; ++ks) {
      aoff[ks][i] = (ar * 8 + ((ks * 4 + hi) ^ (ar & 7))) * 8;
      boff[ks][i] = 8192 + (br * 8 + ((ks * 4 + hi) ^ (br & 7))) * 8;
    }
  }

  f32x4 acc[4][4];
#pragma unroll
  for (int i = 0; i < 4; ++i)
#pragma unroll
    for (int j = 0; j < 4; ++j) acc[i][j] = (f32x4){0.f, 0.f, 0.f, 0.f};

#define SG_A(buf, kt) do { _Pragma("unroll") \
    for (int i_ = 0; i_ < 4; ++i_) \
      g2l16(Ga + (size_t)i_ * 32 * Kc + (kt) * 64, &lds[buf][(i_ * 256 + tid) * 8]); } while (0)
#define SG_B(buf, kt) do { _Pragma("unroll") \
    for (int i_ = 0; i_ < 4; ++i_) \
      g2l16(Gb + (size_t)i_ * 32 * Kc + (kt) * 64, &lds[buf][8192 + (i_ * 256 + tid) * 8]); } while (0)
#define LD_F(eV, F, kt) do { _Pragma("unroll") \
    for (int i_ = 0; i_ < 4; ++i_) { \
      eV[2 * i_]     = *(const float4*)((F) + (size_t)i_ * 32 * Kc + (kt) * 64); \
      eV[2 * i_ + 1] = *(const float4*)((F) + (size_t)i_ * 32 * Kc + (kt) * 64 + 4); } } while (0)
#define WR_F(buf, opb, eV) do { _Pragma("unroll") \
    for (int i_ = 0; i_ < 4; ++i_) \
      *(short8*)&lds[buf][(opb) + (i_ * 256 + tid) * 8] = cvt8(eV[2 * i_], eV[2 * i_ + 1]); } while (0)

  {
    float4 e[8];
    if (MODE == 1) {
      SG_B(0, 0); LD_F(e, Fa, 0); WR_F(0, 0, e);
      SG_B(1, 1); LD_F(e, Fa, 1); WR_F(1, 0, e);
    } else {
      SG_A(0, 0); SG_B(0, 0);
      SG_A(1, 1); SG_B(1, 1);
    }
  }

  int cur = 0;
#pragma unroll 1
  for (int t = 0; t < 8; ++t) {
    if (t == 7)            VMCNT0();
    else if (MODE == 0)    VMCNT8();
    else                   VMCNT4();
    LGKM0();
    BARRIER();

    const short* L = lds[cur];
    const bool pf = (t < 6);
    float4 e[8];

    short8 af[4], bq[4];
#pragma unroll
    for (int i = 0; i < 4; ++i) af[i] = *(const short8*)(L + aoff[0][i]);
#pragma unroll
    for (int j = 0; j < 4; ++j) bq[j] = *(const short8*)(L + boff[0][j]);
    if (pf && MODE == 1) LD_F(e, Fa, t + 2);
#pragma unroll
    for (int i = 0; i < 4; ++i)
#pragma unroll
      for (int j = 0; j < 4; ++j)
        acc[i][j] = __builtin_amdgcn_mfma_f32_16x16x32_bf16(af[i], bq[j], acc[i][j], 0, 0, 0);
#pragma unroll
    for (int i = 0; i < 4; ++i) af[i] = *(const short8*)(L + aoff[1][i]);
#pragma unroll
    for (int j = 0; j < 4; ++j) bq[j] = *(const short8*)(L + boff[1][j]);
#pragma unroll
    for (int i = 0; i < 4; ++i)
#pragma unroll
      for (int j = 0; j < 4; ++j)
        acc[i][j] = __builtin_amdgcn_mfma_f32_16x16x32_bf16(af[i], bq[j], acc[i][j], 0, 0, 0);

    BARRIER();

    if (pf) {
      if (MODE == 1)      { SG_B(cur, t + 2); WR_F(cur, 0, e); }
      else                { SG_A(cur, t + 2); SG_B(cur, t + 2); }
    }
    cur ^= 1;
  }
#undef SG_A
#undef SG_B
#undef LD_F
#undef WR_F

  short* C = (short*)(z ? C1 : C0);
#pragma unroll
  for (int i = 0; i < 4; ++i)
#pragma unroll
    for (int r = 0; r < 4; ++r) {
      const size_t row = m0 + wr * 64 + i * 16 + hi * 4 + r;
#pragma unroll
      for (int j = 0; j < 4; ++j)
        C[row * Dd + n0 + wn * 64 + j * 16 + lo] = f2bf(acc[i][j][r]);
    }
}

// ===========================================================================
// corr: per batch z, mv[z][(t-s)%1024] += T[z,t,:]·K[z,s,:].
// r10's 256x256 structure SPLIT-K x2 -> 512 blocks = 2 blocks/CU so one
// block's barrier drain is covered by the other block's waves (the
// single-block-per-CU serial-drain was r10's 72us wall).  Per block:
// K-half koff, 8 K-steps of BK=32, 2-slot dbuf, fused fp32-K cvt staging,
// 511-bin diagonal epilogue (atomic -> split-K-safe for free).
// ===========================================================================
__global__ __launch_bounds__(1024) void corr_gemm(
    const short* __restrict__ T, const float* __restrict__ Kf,
    float* __restrict__ mv)
{
  __shared__ short lds[2][16384];        // per buf: A(T) [0,8192), B(K) [8192,16384)
  __shared__ float bins[512];

  const int tid = threadIdx.x;
  // 512 blocks, chunk-64 XCD swizzle: each XCD covers 2 whole batches
  const int fb = blockIdx.x;
  const int s  = (fb & 7) * 64 + (fb >> 3);
  const int z    = s >> 5;               // batch (32 blocks/batch)
  const int koff = ((s >> 4) & 1) * 256; // K-half
  const int m0 = ((s >> 2) & 3) * 256;   // T rows (t)
  const int n0 = (s & 3) * 256;          // K rows (s)

  const short* Ab = T  + (size_t)z * Ll * Dd;
  const float* Bf = Kf + (size_t)z * Ll * Dd;

  const int rS  = tid >> 2;
  const int c8S = (tid & 3) ^ ((rS >> 1) & 3);
  const short* gA = Ab + (size_t)(m0 + rS) * Dd + koff + c8S * 8;
  const float* gB = Bf + (size_t)(n0 + rS) * Dd + koff + c8S * 8;
  const int dB = 8192 + tid * 8;

  const int lane = tid & 63;
  const int wid  = tid >> 6;
  const int wm = wid >> 2, wn = wid & 3;
  const int lo = lane & 15, hi = lane >> 4;
  int aoff[4], boff[4];
#pragma unroll
  for (int i = 0; i < 4; ++i) {
    const int ar = wm * 64 + i * 16 + lo;
    aoff[i] = (ar * 4 + (hi ^ ((ar >> 1) & 3))) * 8;
  }
#pragma unroll
  for (int j = 0; j < 4; ++j) {
    const int br = wn * 64 + j * 16 + lo;
    boff[j] = 8192 + (br * 4 + (hi ^ ((br >> 1) & 3))) * 8;
  }

  if (tid < 512) bins[tid] = 0.f;

  f32x4 acc[4][4];
#pragma unroll
  for (int i = 0; i < 4; ++i)
#pragma unroll
    for (int j = 0; j < 4; ++j) acc[i][j] = (f32x4){0.f, 0.f, 0.f, 0.f};

  // prologue: k-tile 0 -> buf 0
  {
    g2l16(gA, &lds[0][tid * 8]);
    const float4 a = *(const float4*)(gB);
    const float4 b = *(const float4*)(gB + 4);
    *(short8*)&lds[0][dB] = cvt8(a, b);
  }
  __syncthreads();

#pragma unroll 1
  for (int t = 0; t < 8; ++t) {
    const int cur = t & 1;
    const short* L = &lds[cur][0];
    short8 af[4], bfr[4];
#pragma unroll
    for (int i = 0; i < 4; ++i) af[i]  = *(const short8*)(L + aoff[i]);
#pragma unroll
    for (int j = 0; j < 4; ++j) bfr[j] = *(const short8*)(L + boff[j]);

    float4 e0, e1;
    if (t < 7) {
      const int ke = (t + 1) * 32;
      g2l16(gA + ke, &lds[cur ^ 1][tid * 8]);
      e0 = *(const float4*)(gB + ke);
      e1 = *(const float4*)(gB + ke + 4);
    }

#pragma unroll
    for (int i = 0; i < 4; ++i)
#pragma unroll
      for (int j = 0; j < 4; ++j)
        acc[i][j] = __builtin_amdgcn_mfma_f32_16x16x32_bf16(af[i], bfr[j], acc[i][j], 0, 0, 0);

    if (t < 7) *(short8*)&lds[cur ^ 1][dB] = cvt8(e0, e1);
    __syncthreads();
  }

  // diagonal pre-reduce by (i-j, r), then LDS bins, then 511 global atomics
  float red[7][4];
#pragma unroll
  for (int d = 0; d < 7; ++d)
#pragma unroll
    for (int r = 0; r < 4; ++r) red[d][r] = 0.f;
#pragma unroll
  for (int i = 0; i < 4; ++i)
#pragma unroll
    for (int j = 0; j < 4; ++j)
#pragma unroll
      for (int r = 0; r < 4; ++r) red[i - j + 3][r] += acc[i][j][r];

  const int dbase = 255 + (wm - wn) * 64 + 4 * hi - lo;
#pragma unroll
  for (int d = 0; d < 7; ++d)
#pragma unroll
    for (int r = 0; r < 4; ++r)
      atomicAdd(&bins[dbase + 16 * (d - 3) + r], red[d][r]);
  __syncthreads();
  if (tid < 511) {
    const int l = (m0 - n0 + tid - 255) & (Ll - 1);
    atomicAdd(&mv[z * Ll + l], bins[tid]);
  }
}

// ===========================================================================
// prep: z in {0,1,2}: straight fp32->bf16 cvt of WQ/WK/WV; z==3: transposed
// cvt of Wfc.  z==0 zeroes mv.
// ===========================================================================
__global__ __launch_bounds__(256) void prep(
    const float* __restrict__ WQ, const float* __restrict__ WK,
    const float* __restrict__ WV, const float* __restrict__ Wfc,
    short* __restrict__ wqb, short* __restrict__ wkb,
    short* __restrict__ wvb, short* __restrict__ wtf,
    float* __restrict__ mv)
{
  const int z = blockIdx.z;
  const int tx = threadIdx.x & 31, ty = threadIdx.x >> 5;
  const int bx = blockIdx.x, by = blockIdx.y;
  if (z < 3) {
    const float* W = (z == 0) ? WQ : (z == 1) ? WK : WV;
    short* O = (z == 0) ? wqb : (z == 1) ? wkb : wvb;
#pragma unroll
    for (int s = 0; s < 32; s += 8) {
      const size_t o = (size_t)(by * 32 + ty + s) * 512 + bx * 32 + tx;
      O[o] = f2bf(W[o]);
    }
    if (z == 0 && threadIdx.x < 64) {
      const int fb = by * 16 + bx;
      mv[fb * 64 + threadIdx.x] = 0.f;
    }
  } else {
    __shared__ float t[32][33];
#pragma unroll
    for (int s = 0; s < 32; s += 8)
      t[ty + s][tx] = Wfc[(size_t)(by * 32 + ty + s) * 512 + bx * 32 + tx];
    __syncthreads();
#pragma unroll
    for (int s = 0; s < 32; s += 8)
      wtf[(size_t)(bx * 32 + ty + s) * 512 + by * 32 + tx] = f2bf(t[tx][ty + s]);
  }
}

__global__ __launch_bounds__(1024) void topk_softmax(
    const float* __restrict__ mean_value,
    int* __restrict__ idx_out, float* __restrict__ w_out)
{
  __shared__ float vals[1024];
  __shared__ int   inds[1024];
  __shared__ float bm[1024];
  __shared__ int   topi[TOPK];
  const int t = threadIdx.x;
  float s = 0.f;
  for (int b = 0; b < Bb; ++b) s += mean_value[b * Ll + t];
  bm[t] = s;
  __syncthreads();
  for (int k = 0; k < TOPK; ++k) {
    bool taken = false;
    for (int j = 0; j < k; ++j) taken |= (topi[j] == t);
    vals[t] = taken ? -INFINITY : bm[t];
    inds[t] = t;
    __syncthreads();
    for (int stride = 512; stride > 0; stride >>= 1) {
      if (t < stride) {
        if (vals[t + stride] > vals[t]) { vals[t] = vals[t + stride]; inds[t] = inds[t + stride]; }
      }
      __syncthreads();
    }
    if (t == 0) topi[k] = inds[0];
    __syncthreads();
  }
  if (t < TOPK) idx_out[t] = topi[t];
  if (t < Bb) {
    float wv[TOPK], mx = -INFINITY;
#pragma unroll
    for (int k = 0; k < TOPK; ++k) {
      wv[k] = mean_value[t * Ll + topi[k]] * (1.f / 512.f);
      mx = fmaxf(mx, wv[k]);
    }
    float sum = 0.f;
#pragma unroll
    for (int k = 0; k < TOPK; ++k) { wv[k] = expf(wv[k] - mx); sum += wv[k]; }
#pragma unroll
    for (int k = 0; k < TOPK; ++k) w_out[t * TOPK + k] = wv[k] / sum;
  }
}

// out[b][l][c] = sum_k w[b][k] * bf2f(U[b][(l+idx_k)%L][c])   (fp32 out)
__global__ __launch_bounds__(256) void gather_out(
    const short* __restrict__ U, const float* __restrict__ w,
    const int* __restrict__ idx, float* __restrict__ out)
{
  const int b = blockIdx.y;
  __shared__ float ww[8];
  __shared__ int   ii[8];
  if (threadIdx.x < TOPK) { ww[threadIdx.x] = w[b * TOPK + threadIdx.x]; ii[threadIdx.x] = idx[threadIdx.x]; }
  __syncthreads();
  const int l = blockIdx.x * 4 + (threadIdx.x >> 6);
  const int c = (threadIdx.x & 63) * 8;
  const short* ub = U + (size_t)b * Ll * Dd;
  float a[8] = {};
#pragma unroll
  for (int k = 0; k < TOPK; ++k) {
    const short8 vv = *(const short8*)&ub[(size_t)((l + ii[k]) & (Ll - 1)) * Dd + c];
    const float wk = ww[k];
#pragma unroll
    for (int e = 0; e < 8; ++e) a[e] = fmaf(wk, bf2f(vv[e]), a[e]);
  }
  float* op = &out[((size_t)b * Ll + l) * Dd + c];
  *(float4*)op       = make_float4(a[0], a[1], a[2], a[3]);
  *(float4*)(op + 4) = make_float4(a[4], a[5], a[6], a[7]);
}

}  // namespace

extern "C" void kernel_launch(void* const* d_in, const int* in_sizes, int n_in,
                              void* d_out, int out_size, void* d_ws, size_t ws_size,
                              hipStream_t stream)
{
  const float* Q   = (const float*)d_in[0];
  const float* K   = (const float*)d_in[1];
  const float* V   = (const float*)d_in[2];
  const float* WQ  = (const float*)d_in[4];
  const float* WK  = (const float*)d_in[5];
  const float* WV  = (const float*)d_in[6];
  const float* Wfc = (const float*)d_in[7];
  float* out = (float*)d_out;

  char* ws = (char*)d_ws;
  const size_t SB = (size_t)Bb * Ll * Dd * sizeof(short);   // 16 MiB
  short* T    = (short*)(ws);
  short* U    = (short*)(ws + 1 * SB);
  short* wqb  = (short*)(ws + 2 * SB);
  short* wkb  = wqb + 512 * 512;
  short* wvb  = wkb + 512 * 512;
  short* wtf  = wvb + 512 * 512;
  short* Gt   = wtf + 512 * 512;
  short* Ht   = Gt  + 512 * 512;
  float* mv   = (float*)(Ht + 512 * 512);
  float* w    = mv + Bb * Ll;
  int*   idx  = (int*)(w + 128);

  // weights -> bf16 (wqb/wkb/wvb straight, wtf = Wfc^T), zero mv
  prep<<<dim3(16, 16, 4), 256, 0, stream>>>(WQ, WK, WV, Wfc, wqb, wkb, wvb, wtf, mv);

  // Gt[n][k] = sum_e Wk[n][e]*Wq[k][e] ; Ht[n][k] = sum_e Wfc[e][n]*Wv[k][e]
  g64<0><<<32, 256, 0, stream>>>(wkb, wtf, wqb, wvb, Gt, Ht);

  // T = bf16(Q @ Gt^T) ; U = bf16(V @ Ht^T)
  g64<1><<<dim3(512, 1, 2), 256, 0, stream>>>(Q, V, Gt, Ht, T, U);

  // mv[b][(t-s)%L] += T[b,t,:] · bf16(K[b,s,:])  (256^2 tiles, split-K x2,
  // 512 blocks = 2 blocks/CU: cross-block overlap covers the barrier drain)
  corr_gemm<<<512, 1024, 0, stream>>>(T, K, mv);

  topk_softmax<<<1, 1024, 0, stream>>>(mv, idx, w);

  // out[b,l,:] = sum_k w_k * U[b,(l+d_k)%L,:]
  gather_out<<<dim3(Ll / 4, Bb), 256, 0, stream>>>(U, w, idx, out);
}

// Round 13
// 137.154 us; speedup vs baseline: 1.2346x; 1.2346x over previous
//
#include <hip/hip_runtime.h>
#include <math.h>

namespace {

constexpr int Bb = 16;
constexpr int Ll = 1024;
constexpr int Dd = 512;
constexpr int TOPK = 6;
constexpr int Kc = 512;

typedef short  short8 __attribute__((ext_vector_type(8)));
typedef float  f32x4  __attribute__((ext_vector_type(4)));

__device__ __forceinline__ short f2bf(float x) {
  unsigned u = __builtin_bit_cast(unsigned, x);
  u += 0x7fffu + ((u >> 16) & 1u);          // RNE
  return (short)(u >> 16);
}
__device__ __forceinline__ float bf2f(short b) {
  unsigned u = ((unsigned)(unsigned short)b) << 16;
  return __builtin_bit_cast(float, u);
}
__device__ __forceinline__ void g2l16(const void* g, void* l) {
  __builtin_amdgcn_global_load_lds(
      (const __attribute__((address_space(1))) unsigned*)g,
      (__attribute__((address_space(3))) unsigned*)l, 16, 0, 0);
}
__device__ __forceinline__ short8 cvt8(float4 a, float4 b) {
  short8 o;
  o[0] = f2bf(a.x); o[1] = f2bf(a.y); o[2] = f2bf(a.z); o[3] = f2bf(a.w);
  o[4] = f2bf(b.x); o[5] = f2bf(b.y); o[6] = f2bf(b.z); o[7] = f2bf(b.w);
  return o;
}

#define BARRIER() do { asm volatile("" ::: "memory"); \
    __builtin_amdgcn_s_barrier(); \
    asm volatile("" ::: "memory"); } while (0)
#define VMCNT8() asm volatile("s_waitcnt vmcnt(8)" ::: "memory")
#define VMCNT4() asm volatile("s_waitcnt vmcnt(4)" ::: "memory")
#define VMCNT0() asm volatile("s_waitcnt vmcnt(0)" ::: "memory")
#define LGKM0()  do { asm volatile("s_waitcnt lgkmcnt(0)" ::: "memory"); \
    __builtin_amdgcn_sched_barrier(0); } while (0)

// ===========================================================================
// r10's g64 (refcheck'd): NT GEMM, 128x128 tile, BK=64 (8 K-steps), 256 thr
// (4 waves, 2m x 2n of 64x64), depth-2 LDS ring, counted entry-vmcnt,
// XOR-swizzled LDS.
// MODE 0: tiny — A,B bf16; C bf16.   z: 0 = Gt, 1 = Ht       (32 blocks)
// MODE 1: front — A fp32 (split-stage + cvt), B bf16; C bf16.
//         z: 0 = T = Q@Gt^T, 1 = U = V@Ht^T; z==2: K fp32 -> kb bf16 copy.
// ===========================================================================
template<int MODE>
__global__ __launch_bounds__(256) void g64(
    const void* __restrict__ A0, const void* __restrict__ A1,
    const short* __restrict__ B0, const short* __restrict__ B1,
    void* __restrict__ C0, void* __restrict__ C1,
    const float* __restrict__ KfIn, short* __restrict__ kbOut)
{
  __shared__ short lds[2][16384];   // per buf: A [0,8192), B [8192,16384)

  const int tid = threadIdx.x;
  int z, m0, n0;
  if (MODE == 0) {
    z = blockIdx.x >> 4;
    const int s = blockIdx.x & 15;
    m0 = (s >> 2) * 128;  n0 = (s & 3) * 128;
  } else {
    z = blockIdx.z;
    if (z == 2) {                              // K fp32 -> bf16 copy slice
      const int base = blockIdx.x * 256 + tid; // 512 blk x 256 thr = 131072
#pragma unroll
      for (int it = 0; it < 8; ++it) {
        const size_t i8 = (size_t)base + (size_t)it * 131072;
        const float4 a = *(const float4*)(KfIn + i8 * 8);
        const float4 b = *(const float4*)(KfIn + i8 * 8 + 4);
        *(short8*)&kbOut[i8 * 8] = cvt8(a, b);
      }
      return;
    }
    const int fb = blockIdx.x;                 // 512, XCD chunk = 64
    const int s  = (fb & 7) * 64 + (fb >> 3);
    m0 = (s >> 2) * 128;  n0 = (s & 3) * 128;
  }

  const int rS  = tid >> 3;                    // 0..31
  const int c8S = (tid & 7) ^ (rS & 7);        // swizzled source 16B-slot
  const short* Ga = nullptr;  const float* Fa = nullptr;
  const short* Gb = nullptr;
  if (MODE == 0) {
    Ga = (const short*)(z ? A1 : A0) + (size_t)(m0 + rS) * Kc + c8S * 8;
    Gb = (z ? B1 : B0) + (size_t)(n0 + rS) * Kc + c8S * 8;
  } else {
    Fa = (const float*)(z ? A1 : A0) + (size_t)(m0 + rS) * Kc + c8S * 8;
    Gb = (z ? B1 : B0) + (size_t)(n0 + rS) * Kc + c8S * 8;
  }

  const int lane = tid & 63;
  const int wid  = tid >> 6;
  const int wr = wid >> 1, wn = wid & 1;
  const int lo = lane & 15, hi = lane >> 4;
  int aoff[2][4], boff[2][4];
#pragma unroll
  for (int i = 0; i < 4; ++i) {
    const int ar = wr * 64 + i * 16 + lo;
    const int br = wn * 64 + i * 16 + lo;
#pragma unroll
    for (int ks = 0; ks < 2; ++ks) {
      aoff[ks][i] = (ar * 8 + ((ks * 4 + hi) ^ (ar & 7))) * 8;
      boff[ks][i] = 8192 + (br * 8 + ((ks * 4 + hi) ^ (br & 7))) * 8;
    }
  }

  f32x4 acc[4][4];
#pragma unroll
  for (int i = 0; i < 4; ++i)
#pragma unroll
    for (int j = 0; j < 4; ++j) acc[i][j] = (f32x4){0.f, 0.f, 0.f, 0.f};

#define SG_A(buf, kt) do { _Pragma("unroll") \
    for (int i_ = 0; i_ < 4; ++i_) \
      g2l16(Ga + (size_t)i_ * 32 * Kc + (kt) * 64, &lds[buf][(i_ * 256 + tid) * 8]); } while (0)
#define SG_B(buf, kt) do { _Pragma("unroll") \
    for (int i_ = 0; i_ < 4; ++i_) \
      g2l16(Gb + (size_t)i_ * 32 * Kc + (kt) * 64, &lds[buf][8192 + (i_ * 256 + tid) * 8]); } while (0)
#define LD_F(eV, F, kt) do { _Pragma("unroll") \
    for (int i_ = 0; i_ < 4; ++i_) { \
      eV[2 * i_]     = *(const float4*)((F) + (size_t)i_ * 32 * Kc + (kt) * 64); \
      eV[2 * i_ + 1] = *(const float4*)((F) + (size_t)i_ * 32 * Kc + (kt) * 64 + 4); } } while (0)
#define WR_F(buf, opb, eV) do { _Pragma("unroll") \
    for (int i_ = 0; i_ < 4; ++i_) \
      *(short8*)&lds[buf][(opb) + (i_ * 256 + tid) * 8] = cvt8(eV[2 * i_], eV[2 * i_ + 1]); } while (0)

  {
    float4 e[8];
    if (MODE == 1) {
      SG_B(0, 0); LD_F(e, Fa, 0); WR_F(0, 0, e);
      SG_B(1, 1); LD_F(e, Fa, 1); WR_F(1, 0, e);
    } else {
      SG_A(0, 0); SG_B(0, 0);
      SG_A(1, 1); SG_B(1, 1);
    }
  }

  int cur = 0;
#pragma unroll 1
  for (int t = 0; t < 8; ++t) {
    if (t == 7)            VMCNT0();
    else if (MODE == 0)    VMCNT8();
    else                   VMCNT4();
    LGKM0();
    BARRIER();

    const short* L = lds[cur];
    const bool pf = (t < 6);
    float4 e[8];

    short8 af[4], bq[4];
#pragma unroll
    for (int i = 0; i < 4; ++i) af[i] = *(const short8*)(L + aoff[0][i]);
#pragma unroll
    for (int j = 0; j < 4; ++j) bq[j] = *(const short8*)(L + boff[0][j]);
    if (pf && MODE == 1) LD_F(e, Fa, t + 2);
#pragma unroll
    for (int i = 0; i < 4; ++i)
#pragma unroll
      for (int j = 0; j < 4; ++j)
        acc[i][j] = __builtin_amdgcn_mfma_f32_16x16x32_bf16(af[i], bq[j], acc[i][j], 0, 0, 0);
#pragma unroll
    for (int i = 0; i < 4; ++i) af[i] = *(const short8*)(L + aoff[1][i]);
#pragma unroll
    for (int j = 0; j < 4; ++j) bq[j] = *(const short8*)(L + boff[1][j]);
#pragma unroll
    for (int i = 0; i < 4; ++i)
#pragma unroll
      for (int j = 0; j < 4; ++j)
        acc[i][j] = __builtin_amdgcn_mfma_f32_16x16x32_bf16(af[i], bq[j], acc[i][j], 0, 0, 0);

    BARRIER();

    if (pf) {
      if (MODE == 1)      { SG_B(cur, t + 2); WR_F(cur, 0, e); }
      else                { SG_A(cur, t + 2); SG_B(cur, t + 2); }
    }
    cur ^= 1;
  }
#undef SG_A
#undef SG_B
#undef LD_F
#undef WR_F

  short* C = (short*)(z ? C1 : C0);
#pragma unroll
  for (int i = 0; i < 4; ++i)
#pragma unroll
    for (int r = 0; r < 4; ++r) {
      const size_t row = m0 + wr * 64 + i * 16 + hi * 4 + r;
#pragma unroll
      for (int j = 0; j < 4; ++j)
        C[row * Dd + n0 + wn * 64 + j * 16 + lo] = f2bf(acc[i][j][r]);
    }
}

// ===========================================================================
// corr: per batch z, mv[z][(t-s)%1024] += T[z,t,:]·kb[z,s,:]  (both bf16).
// r6's PASSING corr structure verbatim: 256x256 tile, 1024 thr (16 waves
// 4m x 4n of 64x64), BK=32, 2-slot dbuf, pure-g2l16 staging for BOTH
// operands, one barrier per K-step, 511-bin diagonal epilogue.
// Only delta vs r6: B reads pre-converted kb (bf16) instead of staging
// fp32 K through registers (r10) — shorter drain chain, 2/3 the bytes.
// 256 blocks (16/batch), chunk-32 XCD swizzle (2 whole batches per XCD).
// ===========================================================================
__global__ __launch_bounds__(1024) void corr_gemm(
    const short* __restrict__ T, const short* __restrict__ kb,
    float* __restrict__ mv)
{
  __shared__ short lds[2][16384];        // per buf: A(T) [0,8192), B(kb) [8192,16384)
  __shared__ float bins[512];

  const int tid = threadIdx.x;
  const int fb = blockIdx.x;
  const int s  = (fb & 7) * 32 + (fb >> 3);
  const int z  = s >> 4;
  const int m0 = ((s >> 2) & 3) * 256;   // T rows (t)
  const int n0 = (s & 3) * 256;          // kb rows (s)

  const short* Ab = T  + (size_t)z * Ll * Dd;
  const short* Bp = kb + (size_t)z * Ll * Dd;

  const int rS  = tid >> 2;              // 0..255
  const int c8S = (tid & 3) ^ ((rS >> 1) & 3);
  const short* gA = Ab + (size_t)(m0 + rS) * Dd + c8S * 8;
  const short* gB = Bp + (size_t)(n0 + rS) * Dd + c8S * 8;
  const int dA = tid * 8, dB = 8192 + tid * 8;

  const int lane = tid & 63;
  const int wid  = tid >> 6;
  const int wm = wid >> 2, wn = wid & 3;
  const int lo = lane & 15, hi = lane >> 4;
  int aoff[4], boff[4];
#pragma unroll
  for (int i = 0; i < 4; ++i) {
    const int ar = wm * 64 + i * 16 + lo;
    aoff[i] = (ar * 4 + (hi ^ ((ar >> 1) & 3))) * 8;
  }
#pragma unroll
  for (int j = 0; j < 4; ++j) {
    const int br = wn * 64 + j * 16 + lo;
    boff[j] = 8192 + (br * 4 + (hi ^ ((br >> 1) & 3))) * 8;
  }

  if (tid < 512) bins[tid] = 0.f;

  f32x4 acc[4][4];
#pragma unroll
  for (int i = 0; i < 4; ++i)
#pragma unroll
    for (int j = 0; j < 4; ++j) acc[i][j] = (f32x4){0.f, 0.f, 0.f, 0.f};

  g2l16(gA, &lds[0][dA]);
  g2l16(gB, &lds[0][dB]);
  __syncthreads();

#pragma unroll 1
  for (int t = 0; t < 16; ++t) {
    const int cur = t & 1;
    const short* L = &lds[cur][0];
    short8 af[4], bfr[4];
#pragma unroll
    for (int i = 0; i < 4; ++i) af[i]  = *(const short8*)(L + aoff[i]);
#pragma unroll
    for (int j = 0; j < 4; ++j) bfr[j] = *(const short8*)(L + boff[j]);

    if (t < 15) {
      const int ke = (t + 1) * 32;
      g2l16(gA + ke, &lds[cur ^ 1][dA]);
      g2l16(gB + ke, &lds[cur ^ 1][dB]);
    }

#pragma unroll
    for (int i = 0; i < 4; ++i)
#pragma unroll
      for (int j = 0; j < 4; ++j)
        acc[i][j] = __builtin_amdgcn_mfma_f32_16x16x32_bf16(af[i], bfr[j], acc[i][j], 0, 0, 0);
    __syncthreads();
  }

  // diagonal pre-reduce by (i-j, r), then LDS bins, then 511 global atomics
  float red[7][4];
#pragma unroll
  for (int d = 0; d < 7; ++d)
#pragma unroll
    for (int r = 0; r < 4; ++r) red[d][r] = 0.f;
#pragma unroll
  for (int i = 0; i < 4; ++i)
#pragma unroll
    for (int j = 0; j < 4; ++j)
#pragma unroll
      for (int r = 0; r < 4; ++r) red[i - j + 3][r] += acc[i][j][r];

  const int dbase = 255 + (wm - wn) * 64 + 4 * hi - lo;
#pragma unroll
  for (int d = 0; d < 7; ++d)
#pragma unroll
    for (int r = 0; r < 4; ++r)
      atomicAdd(&bins[dbase + 16 * (d - 3) + r], red[d][r]);
  __syncthreads();
  if (tid < 511) {
    const int l = (m0 - n0 + tid - 255) & (Ll - 1);
    atomicAdd(&mv[z * Ll + l], bins[tid]);
  }
}

// ===========================================================================
// prep: z in {0,1,2}: straight fp32->bf16 cvt of WQ/WK/WV; z==3: transposed
// cvt of Wfc.  z==0 zeroes mv.
// ===========================================================================
__global__ __launch_bounds__(256) void prep(
    const float* __restrict__ WQ, const float* __restrict__ WK,
    const float* __restrict__ WV, const float* __restrict__ Wfc,
    short* __restrict__ wqb, short* __restrict__ wkb,
    short* __restrict__ wvb, short* __restrict__ wtf,
    float* __restrict__ mv)
{
  const int z = blockIdx.z;
  const int tx = threadIdx.x & 31, ty = threadIdx.x >> 5;
  const int bx = blockIdx.x, by = blockIdx.y;
  if (z < 3) {
    const float* W = (z == 0) ? WQ : (z == 1) ? WK : WV;
    short* O = (z == 0) ? wqb : (z == 1) ? wkb : wvb;
#pragma unroll
    for (int s = 0; s < 32; s += 8) {
      const size_t o = (size_t)(by * 32 + ty + s) * 512 + bx * 32 + tx;
      O[o] = f2bf(W[o]);
    }
    if (z == 0 && threadIdx.x < 64) {
      const int fb = by * 16 + bx;
      mv[fb * 64 + threadIdx.x] = 0.f;
    }
  } else {
    __shared__ float t[32][33];
#pragma unroll
    for (int s = 0; s < 32; s += 8)
      t[ty + s][tx] = Wfc[(size_t)(by * 32 + ty + s) * 512 + bx * 32 + tx];
    __syncthreads();
#pragma unroll
    for (int s = 0; s < 32; s += 8)
      wtf[(size_t)(bx * 32 + ty + s) * 512 + by * 32 + tx] = f2bf(t[tx][ty + s]);
  }
}

__global__ __launch_bounds__(1024) void topk_softmax(
    const float* __restrict__ mean_value,
    int* __restrict__ idx_out, float* __restrict__ w_out)
{
  __shared__ float vals[1024];
  __shared__ int   inds[1024];
  __shared__ float bm[1024];
  __shared__ int   topi[TOPK];
  const int t = threadIdx.x;
  float s = 0.f;
  for (int b = 0; b < Bb; ++b) s += mean_value[b * Ll + t];
  bm[t] = s;
  __syncthreads();
  for (int k = 0; k < TOPK; ++k) {
    bool taken = false;
    for (int j = 0; j < k; ++j) taken |= (topi[j] == t);
    vals[t] = taken ? -INFINITY : bm[t];
    inds[t] = t;
    __syncthreads();
    for (int stride = 512; stride > 0; stride >>= 1) {
      if (t < stride) {
        if (vals[t + stride] > vals[t]) { vals[t] = vals[t + stride]; inds[t] = inds[t + stride]; }
      }
      __syncthreads();
    }
    if (t == 0) topi[k] = inds[0];
    __syncthreads();
  }
  if (t < TOPK) idx_out[t] = topi[t];
  if (t < Bb) {
    float wv[TOPK], mx = -INFINITY;
#pragma unroll
    for (int k = 0; k < TOPK; ++k) {
      wv[k] = mean_value[t * Ll + topi[k]] * (1.f / 512.f);
      mx = fmaxf(mx, wv[k]);
    }
    float sum = 0.f;
#pragma unroll
    for (int k = 0; k < TOPK; ++k) { wv[k] = expf(wv[k] - mx); sum += wv[k]; }
#pragma unroll
    for (int k = 0; k < TOPK; ++k) w_out[t * TOPK + k] = wv[k] / sum;
  }
}

// out[b][l][c] = sum_k w[b][k] * bf2f(U[b][(l+idx_k)%L][c])   (fp32 out)
__global__ __launch_bounds__(256) void gather_out(
    const short* __restrict__ U, const float* __restrict__ w,
    const int* __restrict__ idx, float* __restrict__ out)
{
  const int b = blockIdx.y;
  __shared__ float ww[8];
  __shared__ int   ii[8];
  if (threadIdx.x < TOPK) { ww[threadIdx.x] = w[b * TOPK + threadIdx.x]; ii[threadIdx.x] = idx[threadIdx.x]; }
  __syncthreads();
  const int l = blockIdx.x * 4 + (threadIdx.x >> 6);
  const int c = (threadIdx.x & 63) * 8;
  const short* ub = U + (size_t)b * Ll * Dd;
  float a[8] = {};
#pragma unroll
  for (int k = 0; k < TOPK; ++k) {
    const short8 vv = *(const short8*)&ub[(size_t)((l + ii[k]) & (Ll - 1)) * Dd + c];
    const float wk = ww[k];
#pragma unroll
    for (int e = 0; e < 8; ++e) a[e] = fmaf(wk, bf2f(vv[e]), a[e]);
  }
  float* op = &out[((size_t)b * Ll + l) * Dd + c];
  *(float4*)op       = make_float4(a[0], a[1], a[2], a[3]);
  *(float4*)(op + 4) = make_float4(a[4], a[5], a[6], a[7]);
}

}  // namespace

extern "C" void kernel_launch(void* const* d_in, const int* in_sizes, int n_in,
                              void* d_out, int out_size, void* d_ws, size_t ws_size,
                              hipStream_t stream)
{
  const float* Q   = (const float*)d_in[0];
  const float* K   = (const float*)d_in[1];
  const float* V   = (const float*)d_in[2];
  const float* WQ  = (const float*)d_in[4];
  const float* WK  = (const float*)d_in[5];
  const float* WV  = (const float*)d_in[6];
  const float* Wfc = (const float*)d_in[7];
  float* out = (float*)d_out;

  char* ws = (char*)d_ws;
  const size_t SB = (size_t)Bb * Ll * Dd * sizeof(short);   // 16 MiB
  short* T    = (short*)(ws);
  short* U    = (short*)(ws + 1 * SB);
  short* kb   = (short*)(ws + 2 * SB);
  short* wqb  = (short*)(ws + 3 * SB);
  short* wkb  = wqb + 512 * 512;
  short* wvb  = wkb + 512 * 512;
  short* wtf  = wvb + 512 * 512;
  short* Gt   = wtf + 512 * 512;
  short* Ht   = Gt  + 512 * 512;
  float* mv   = (float*)(Ht + 512 * 512);
  float* w    = mv + Bb * Ll;
  int*   idx  = (int*)(w + 128);

  // weights -> bf16 (wqb/wkb/wvb straight, wtf = Wfc^T), zero mv
  prep<<<dim3(16, 16, 4), 256, 0, stream>>>(WQ, WK, WV, Wfc, wqb, wkb, wvb, wtf, mv);

  // Gt[n][k] = sum_e Wk[n][e]*Wq[k][e] ; Ht[n][k] = sum_e Wfc[e][n]*Wv[k][e]
  g64<0><<<32, 256, 0, stream>>>(wkb, wtf, wqb, wvb, Gt, Ht, nullptr, nullptr);

  // T = bf16(Q @ Gt^T) ; U = bf16(V @ Ht^T) ; z=2: kb = bf16(K)
  g64<1><<<dim3(512, 1, 3), 256, 0, stream>>>(Q, V, Gt, Ht, T, U, K, kb);

  // mv[b][(t-s)%L] += T[b,t,:] · kb[b,s,:]   (r6's 256^2 corr, both bf16)
  corr_gemm<<<256, 1024, 0, stream>>>(T, kb, mv);

  topk_softmax<<<1, 1024, 0, stream>>>(mv, idx, w);

  // out[b,l,:] = sum_k w_k * U[b,(l+d_k)%L,:]
  gather_out<<<dim3(Ll / 4, Bb), 256, 0, stream>>>(U, w, idx, out);
}

// Round 14
// 136.361 us; speedup vs baseline: 1.2418x; 1.0058x over previous
//
#include <hip/hip_runtime.h>
#include <math.h>

namespace {

constexpr int Bb = 16;
constexpr int Ll = 1024;
constexpr int Dd = 512;
constexpr int TOPK = 6;
constexpr int Kc = 512;

typedef short  short8 __attribute__((ext_vector_type(8)));
typedef float  f32x4  __attribute__((ext_vector_type(4)));

__device__ __forceinline__ short f2bf(float x) {
  unsigned u = __builtin_bit_cast(unsigned, x);
  u += 0x7fffu + ((u >> 16) & 1u);          // RNE
  return (short)(u >> 16);
}
__device__ __forceinline__ float bf2f(short b) {
  unsigned u = ((unsigned)(unsigned short)b) << 16;
  return __builtin_bit_cast(float, u);
}
__device__ __forceinline__ void g2l16(const void* g, void* l) {
  __builtin_amdgcn_global_load_lds(
      (const __attribute__((address_space(1))) unsigned*)g,
      (__attribute__((address_space(3))) unsigned*)l, 16, 0, 0);
}
__device__ __forceinline__ short8 cvt8(float4 a, float4 b) {
  short8 o;
  o[0] = f2bf(a.x); o[1] = f2bf(a.y); o[2] = f2bf(a.z); o[3] = f2bf(a.w);
  o[4] = f2bf(b.x); o[5] = f2bf(b.y); o[6] = f2bf(b.z); o[7] = f2bf(b.w);
  return o;
}

#define BARRIER() do { asm volatile("" ::: "memory"); \
    __builtin_amdgcn_s_barrier(); \
    asm volatile("" ::: "memory"); } while (0)
#define VMCNT8() asm volatile("s_waitcnt vmcnt(8)" ::: "memory")
#define VMCNT4() asm volatile("s_waitcnt vmcnt(4)" ::: "memory")
#define VMCNT0() asm volatile("s_waitcnt vmcnt(0)" ::: "memory")
#define LGKM0()  do { asm volatile("s_waitcnt lgkmcnt(0)" ::: "memory"); \
    __builtin_amdgcn_sched_barrier(0); } while (0)

// ===========================================================================
// r10's g64 (refcheck'd): NT GEMM, 128x128 tile, BK=64 (8 K-steps), 256 thr
// (4 waves, 2m x 2n of 64x64), depth-2 LDS ring, counted entry-vmcnt,
// XOR-swizzled LDS.
// MODE 0: tiny — A,B bf16; C bf16.  blocks 0..31: z0 = Gt, z1 = Ht.
//         blocks 32..543: K fp32 -> kb bf16 copy (runs on otherwise-idle CUs).
// MODE 1: front — A fp32 (split-stage + cvt), B bf16; C bf16.
//         z: 0 = T = Q@Gt^T, 1 = U = V@Ht^T                  (512 x 2 blocks)
// ===========================================================================
template<int MODE>
__global__ __launch_bounds__(256) void g64(
    const void* __restrict__ A0, const void* __restrict__ A1,
    const short* __restrict__ B0, const short* __restrict__ B1,
    void* __restrict__ C0, void* __restrict__ C1,
    const float* __restrict__ KfIn, short* __restrict__ kbOut)
{
  __shared__ short lds[2][16384];   // per buf: A [0,8192), B [8192,16384)

  const int tid = threadIdx.x;
  int z, m0, n0;
  if (MODE == 0) {
    if (blockIdx.x >= 32) {                    // K fp32 -> bf16 copy slice
      const int base = (blockIdx.x - 32) * 256 + tid;   // 512 blk x 256 thr
#pragma unroll
      for (int it = 0; it < 8; ++it) {
        const size_t i8 = (size_t)base + (size_t)it * 131072;
        const float4 a = *(const float4*)(KfIn + i8 * 8);
        const float4 b = *(const float4*)(KfIn + i8 * 8 + 4);
        *(short8*)&kbOut[i8 * 8] = cvt8(a, b);
      }
      return;
    }
    z = blockIdx.x >> 4;
    const int s = blockIdx.x & 15;
    m0 = (s >> 2) * 128;  n0 = (s & 3) * 128;
  } else {
    z = blockIdx.z;
    const int fb = blockIdx.x;                 // 512, XCD chunk = 64
    const int s  = (fb & 7) * 64 + (fb >> 3);
    m0 = (s >> 2) * 128;  n0 = (s & 3) * 128;
  }

  const int rS  = tid >> 3;                    // 0..31
  const int c8S = (tid & 7) ^ (rS & 7);        // swizzled source 16B-slot
  const short* Ga = nullptr;  const float* Fa = nullptr;
  const short* Gb = nullptr;
  if (MODE == 0) {
    Ga = (const short*)(z ? A1 : A0) + (size_t)(m0 + rS) * Kc + c8S * 8;
    Gb = (z ? B1 : B0) + (size_t)(n0 + rS) * Kc + c8S * 8;
  } else {
    Fa = (const float*)(z ? A1 : A0) + (size_t)(m0 + rS) * Kc + c8S * 8;
    Gb = (z ? B1 : B0) + (size_t)(n0 + rS) * Kc + c8S * 8;
  }

  const int lane = tid & 63;
  const int wid  = tid >> 6;
  const int wr = wid >> 1, wn = wid & 1;
  const int lo = lane & 15, hi = lane >> 4;
  int aoff[2][4], boff[2][4];
#pragma unroll
  for (int i = 0; i < 4; ++i) {
    const int ar = wr * 64 + i * 16 + lo;
    const int br = wn * 64 + i * 16 + lo;
#pragma unroll
    for (int ks = 0; ks < 2; ++ks) {
      aoff[ks][i] = (ar * 8 + ((ks * 4 + hi) ^ (ar & 7))) * 8;
      boff[ks][i] = 8192 + (br * 8 + ((ks * 4 + hi) ^ (br & 7))) * 8;
    }
  }

  f32x4 acc[4][4];
#pragma unroll
  for (int i = 0; i < 4; ++i)
#pragma unroll
    for (int j = 0; j < 4; ++j) acc[i][j] = (f32x4){0.f, 0.f, 0.f, 0.f};

#define SG_A(buf, kt) do { _Pragma("unroll") \
    for (int i_ = 0; i_ < 4; ++i_) \
      g2l16(Ga + (size_t)i_ * 32 * Kc + (kt) * 64, &lds[buf][(i_ * 256 + tid) * 8]); } while (0)
#define SG_B(buf, kt) do { _Pragma("unroll") \
    for (int i_ = 0; i_ < 4; ++i_) \
      g2l16(Gb + (size_t)i_ * 32 * Kc + (kt) * 64, &lds[buf][8192 + (i_ * 256 + tid) * 8]); } while (0)
#define LD_F(eV, F, kt) do { _Pragma("unroll") \
    for (int i_ = 0; i_ < 4; ++i_) { \
      eV[2 * i_]     = *(const float4*)((F) + (size_t)i_ * 32 * Kc + (kt) * 64); \
      eV[2 * i_ + 1] = *(const float4*)((F) + (size_t)i_ * 32 * Kc + (kt) * 64 + 4); } } while (0)
#define WR_F(buf, opb, eV) do { _Pragma("unroll") \
    for (int i_ = 0; i_ < 4; ++i_) \
      *(short8*)&lds[buf][(opb) + (i_ * 256 + tid) * 8] = cvt8(eV[2 * i_], eV[2 * i_ + 1]); } while (0)

  {
    float4 e[8];
    if (MODE == 1) {
      SG_B(0, 0); LD_F(e, Fa, 0); WR_F(0, 0, e);
      SG_B(1, 1); LD_F(e, Fa, 1); WR_F(1, 0, e);
    } else {
      SG_A(0, 0); SG_B(0, 0);
      SG_A(1, 1); SG_B(1, 1);
    }
  }

  int cur = 0;
#pragma unroll 1
  for (int t = 0; t < 8; ++t) {
    if (t == 7)            VMCNT0();
    else if (MODE == 0)    VMCNT8();
    else                   VMCNT4();
    LGKM0();
    BARRIER();

    const short* L = lds[cur];
    const bool pf = (t < 6);
    float4 e[8];

    short8 af[4], bq[4];
#pragma unroll
    for (int i = 0; i < 4; ++i) af[i] = *(const short8*)(L + aoff[0][i]);
#pragma unroll
    for (int j = 0; j < 4; ++j) bq[j] = *(const short8*)(L + boff[0][j]);
    if (pf && MODE == 1) LD_F(e, Fa, t + 2);
#pragma unroll
    for (int i = 0; i < 4; ++i)
#pragma unroll
      for (int j = 0; j < 4; ++j)
        acc[i][j] = __builtin_amdgcn_mfma_f32_16x16x32_bf16(af[i], bq[j], acc[i][j], 0, 0, 0);
#pragma unroll
    for (int i = 0; i < 4; ++i) af[i] = *(const short8*)(L + aoff[1][i]);
#pragma unroll
    for (int j = 0; j < 4; ++j) bq[j] = *(const short8*)(L + boff[1][j]);
#pragma unroll
    for (int i = 0; i < 4; ++i)
#pragma unroll
      for (int j = 0; j < 4; ++j)
        acc[i][j] = __builtin_amdgcn_mfma_f32_16x16x32_bf16(af[i], bq[j], acc[i][j], 0, 0, 0);

    BARRIER();

    if (pf) {
      if (MODE == 1)      { SG_B(cur, t + 2); WR_F(cur, 0, e); }
      else                { SG_A(cur, t + 2); SG_B(cur, t + 2); }
    }
    cur ^= 1;
  }
#undef SG_A
#undef SG_B
#undef LD_F
#undef WR_F

  short* C = (short*)(z ? C1 : C0);
#pragma unroll
  for (int i = 0; i < 4; ++i)
#pragma unroll
    for (int r = 0; r < 4; ++r) {
      const size_t row = m0 + wr * 64 + i * 16 + hi * 4 + r;
#pragma unroll
      for (int j = 0; j < 4; ++j)
        C[row * Dd + n0 + wn * 64 + j * 16 + lo] = f2bf(acc[i][j][r]);
    }
}

// ===========================================================================
// corr: per batch z, mv[z][(t-s)%1024] += T[z,t,:]·kb[z,s,:]  (both bf16).
// r13's validated per-wave code (acc[4][4], 64x64 wave tile, same swizzle,
// same 1-barrier K-loop) re-gridded for CO-RESIDENCY: 256x128 tile, 512 thr
// (8 waves, 4m x 2n), __launch_bounds__(512,4) -> <=128 unified regs/wave
// -> 4 waves/SIMD -> TWO blocks/CU genuinely co-resident (LDS 49.5KB x2).
// One block's barrier drain is covered by the other block's waves.
// 512 blocks (32/batch = 4 m-tiles x 8 n-tiles), chunk-64 XCD swizzle.
// Epilogue: bin = 127 + (wm-wn)*64 + 16(i-j) + 4hi + r - lo in [0,382].
// ===========================================================================
__global__ __launch_bounds__(512, 4) void corr_gemm(
    const short* __restrict__ T, const short* __restrict__ kb,
    float* __restrict__ mv)
{
  __shared__ short lds[2][12288];   // per buf: A(T) [0,8192), B(kb) [8192,12288)
  __shared__ float bins[384];

  const int tid = threadIdx.x;
  const int fb = blockIdx.x;              // 512 blocks, chunk-64 XCD swizzle
  const int s  = (fb & 7) * 64 + (fb >> 3);
  const int z  = s >> 5;                  // batch (32 blocks each)
  const int m0 = ((s >> 3) & 3) * 256;    // T rows (t), 4 tiles
  const int n0 = (s & 7) * 128;           // kb rows (s), 8 tiles

  const short* Ab = T  + (size_t)z * Ll * Dd;
  const short* Bp = kb + (size_t)z * Ll * Dd;

  // staging: A rows 0..255 via units {tid, 512+tid}; B rows 0..127 via unit tid
  const int rS  = tid >> 2;               // 0..127
  const int c8S = (tid & 3) ^ ((rS >> 1) & 3);
  const short* gA0 = Ab + (size_t)(m0 + rS) * Dd + c8S * 8;
  const short* gA1 = gA0 + (size_t)128 * Dd;    // rows 128..255, same swizzle
  const short* gB  = Bp + (size_t)(n0 + rS) * Dd + c8S * 8;
  const int dA0 = tid * 8, dA1 = (512 + tid) * 8, dB = 8192 + tid * 8;

  const int lane = tid & 63;
  const int wid  = tid >> 6;              // 0..7
  const int wm = wid >> 1, wn = wid & 1;  // 4m x 2n of 64x64
  const int lo = lane & 15, hi = lane >> 4;
  int aoff[4], boff[4];
#pragma unroll
  for (int i = 0; i < 4; ++i) {
    const int ar = wm * 64 + i * 16 + lo;       // 0..255
    aoff[i] = (ar * 4 + (hi ^ ((ar >> 1) & 3))) * 8;
  }
#pragma unroll
  for (int j = 0; j < 4; ++j) {
    const int br = wn * 64 + j * 16 + lo;       // 0..127
    boff[j] = 8192 + (br * 4 + (hi ^ ((br >> 1) & 3))) * 8;
  }

  if (tid < 384) bins[tid] = 0.f;

  f32x4 acc[4][4];
#pragma unroll
  for (int i = 0; i < 4; ++i)
#pragma unroll
    for (int j = 0; j < 4; ++j) acc[i][j] = (f32x4){0.f, 0.f, 0.f, 0.f};

#define STAGE(buf, t) do { \
    g2l16(gA0 + (t) * 32, &lds[buf][dA0]); \
    g2l16(gA1 + (t) * 32, &lds[buf][dA1]); \
    g2l16(gB  + (t) * 32, &lds[buf][dB]);  } while (0)

  STAGE(0, 0);
  __syncthreads();

#pragma unroll 1
  for (int t = 0; t < 16; ++t) {
    const int cur = t & 1;
    const short* L = &lds[cur][0];
    short8 af[4], bfr[4];
#pragma unroll
    for (int i = 0; i < 4; ++i) af[i]  = *(const short8*)(L + aoff[i]);
#pragma unroll
    for (int j = 0; j < 4; ++j) bfr[j] = *(const short8*)(L + boff[j]);

    if (t < 15) STAGE(cur ^ 1, t + 1);

#pragma unroll
    for (int i = 0; i < 4; ++i)
#pragma unroll
      for (int j = 0; j < 4; ++j)
        acc[i][j] = __builtin_amdgcn_mfma_f32_16x16x32_bf16(af[i], bfr[j], acc[i][j], 0, 0, 0);
    __syncthreads();
  }
#undef STAGE

  // diagonal pre-reduce by (i-j, r), then LDS bins, then 383 global atomics
  float red[7][4];
#pragma unroll
  for (int d = 0; d < 7; ++d)
#pragma unroll
    for (int r = 0; r < 4; ++r) red[d][r] = 0.f;
#pragma unroll
  for (int i = 0; i < 4; ++i)
#pragma unroll
    for (int j = 0; j < 4; ++j)
#pragma unroll
      for (int r = 0; r < 4; ++r) red[i - j + 3][r] += acc[i][j][r];

  const int dbase = 127 + (wm - wn) * 64 + 4 * hi - lo;
#pragma unroll
  for (int d = 0; d < 7; ++d)
#pragma unroll
    for (int r = 0; r < 4; ++r)
      atomicAdd(&bins[dbase + 16 * (d - 3) + r], red[d][r]);
  __syncthreads();
  if (tid < 383) {
    const int l = (m0 - n0 + tid - 127) & (Ll - 1);
    atomicAdd(&mv[z * Ll + l], bins[tid]);
  }
}

// ===========================================================================
// prep: z in {0,1,2}: straight fp32->bf16 cvt of WQ/WK/WV; z==3: transposed
// cvt of Wfc.  z==0 zeroes mv.
// ===========================================================================
__global__ __launch_bounds__(256) void prep(
    const float* __restrict__ WQ, const float* __restrict__ WK,
    const float* __restrict__ WV, const float* __restrict__ Wfc,
    short* __restrict__ wqb, short* __restrict__ wkb,
    short* __restrict__ wvb, short* __restrict__ wtf,
    float* __restrict__ mv)
{
  const int z = blockIdx.z;
  const int tx = threadIdx.x & 31, ty = threadIdx.x >> 5;
  const int bx = blockIdx.x, by = blockIdx.y;
  if (z < 3) {
    const float* W = (z == 0) ? WQ : (z == 1) ? WK : WV;
    short* O = (z == 0) ? wqb : (z == 1) ? wkb : wvb;
#pragma unroll
    for (int s = 0; s < 32; s += 8) {
      const size_t o = (size_t)(by * 32 + ty + s) * 512 + bx * 32 + tx;
      O[o] = f2bf(W[o]);
    }
    if (z == 0 && threadIdx.x < 64) {
      const int fb = by * 16 + bx;
      mv[fb * 64 + threadIdx.x] = 0.f;
    }
  } else {
    __shared__ float t[32][33];
#pragma unroll
    for (int s = 0; s < 32; s += 8)
      t[ty + s][tx] = Wfc[(size_t)(by * 32 + ty + s) * 512 + bx * 32 + tx];
    __syncthreads();
#pragma unroll
    for (int s = 0; s < 32; s += 8)
      wtf[(size_t)(bx * 32 + ty + s) * 512 + by * 32 + tx] = f2bf(t[tx][ty + s]);
  }
}

__global__ __launch_bounds__(1024) void topk_softmax(
    const float* __restrict__ mean_value,
    int* __restrict__ idx_out, float* __restrict__ w_out)
{
  __shared__ float vals[1024];
  __shared__ int   inds[1024];
  __shared__ float bm[1024];
  __shared__ int   topi[TOPK];
  const int t = threadIdx.x;
  float s = 0.f;
  for (int b = 0; b < Bb; ++b) s += mean_value[b * Ll + t];
  bm[t] = s;
  __syncthreads();
  for (int k = 0; k < TOPK; ++k) {
    bool taken = false;
    for (int j = 0; j < k; ++j) taken |= (topi[j] == t);
    vals[t] = taken ? -INFINITY : bm[t];
    inds[t] = t;
    __syncthreads();
    for (int stride = 512; stride > 0; stride >>= 1) {
      if (t < stride) {
        if (vals[t + stride] > vals[t]) { vals[t] = vals[t + stride]; inds[t] = inds[t + stride]; }
      }
      __syncthreads();
    }
    if (t == 0) topi[k] = inds[0];
    __syncthreads();
  }
  if (t < TOPK) idx_out[t] = topi[t];
  if (t < Bb) {
    float wv[TOPK], mx = -INFINITY;
#pragma unroll
    for (int k = 0; k < TOPK; ++k) {
      wv[k] = mean_value[t * Ll + topi[k]] * (1.f / 512.f);
      mx = fmaxf(mx, wv[k]);
    }
    float sum = 0.f;
#pragma unroll
    for (int k = 0; k < TOPK; ++k) { wv[k] = expf(wv[k] - mx); sum += wv[k]; }
#pragma unroll
    for (int k = 0; k < TOPK; ++k) w_out[t * TOPK + k] = wv[k] / sum;
  }
}

// out[b][l][c] = sum_k w[b][k] * bf2f(U[b][(l+idx_k)%L][c])   (fp32 out)
__global__ __launch_bounds__(256) void gather_out(
    const short* __restrict__ U, const float* __restrict__ w,
    const int* __restrict__ idx, float* __restrict__ out)
{
  const int b = blockIdx.y;
  __shared__ float ww[8];
  __shared__ int   ii[8];
  if (threadIdx.x < TOPK) { ww[threadIdx.x] = w[b * TOPK + threadIdx.x]; ii[threadIdx.x] = idx[threadIdx.x]; }
  __syncthreads();
  const int l = blockIdx.x * 4 + (threadIdx.x >> 6);
  const int c = (threadIdx.x & 63) * 8;
  const short* ub = U + (size_t)b * Ll * Dd;
  float a[8] = {};
#pragma unroll
  for (int k = 0; k < TOPK; ++k) {
    const short8 vv = *(const short8*)&ub[(size_t)((l + ii[k]) & (Ll - 1)) * Dd + c];
    const float wk = ww[k];
#pragma unroll
    for (int e = 0; e < 8; ++e) a[e] = fmaf(wk, bf2f(vv[e]), a[e]);
  }
  float* op = &out[((size_t)b * Ll + l) * Dd + c];
  *(float4*)op       = make_float4(a[0], a[1], a[2], a[3]);
  *(float4*)(op + 4) = make_float4(a[4], a[5], a[6], a[7]);
}

}  // namespace

extern "C" void kernel_launch(void* const* d_in, const int* in_sizes, int n_in,
                              void* d_out, int out_size, void* d_ws, size_t ws_size,
                              hipStream_t stream)
{
  const float* Q   = (const float*)d_in[0];
  const float* K   = (const float*)d_in[1];
  const float* V   = (const float*)d_in[2];
  const float* WQ  = (const float*)d_in[4];
  const float* WK  = (const float*)d_in[5];
  const float* WV  = (const float*)d_in[6];
  const float* Wfc = (const float*)d_in[7];
  float* out = (float*)d_out;

  char* ws = (char*)d_ws;
  const size_t SB = (size_t)Bb * Ll * Dd * sizeof(short);   // 16 MiB
  short* T    = (short*)(ws);
  short* U    = (short*)(ws + 1 * SB);
  short* kb   = (short*)(ws + 2 * SB);
  short* wqb  = (short*)(ws + 3 * SB);
  short* wkb  = wqb + 512 * 512;
  short* wvb  = wkb + 512 * 512;
  short* wtf  = wvb + 512 * 512;
  short* Gt   = wtf + 512 * 512;
  short* Ht   = Gt  + 512 * 512;
  float* mv   = (float*)(Ht + 512 * 512);
  float* w    = mv + Bb * Ll;
  int*   idx  = (int*)(w + 128);

  // weights -> bf16 (wqb/wkb/wvb straight, wtf = Wfc^T), zero mv
  prep<<<dim3(16, 16, 4), 256, 0, stream>>>(WQ, WK, WV, Wfc, wqb, wkb, wvb, wtf, mv);

  // blocks 0..31: Gt = WK@wqb^T, Ht = wtf@wvb^T; blocks 32..543: kb = bf16(K)
  g64<0><<<544, 256, 0, stream>>>(wkb, wtf, wqb, wvb, Gt, Ht, K, kb);

  // T = bf16(Q @ Gt^T) ; U = bf16(V @ Ht^T)
  g64<1><<<dim3(512, 1, 2), 256, 0, stream>>>(Q, V, Gt, Ht, T, U, nullptr, nullptr);

  // mv[b][(t-s)%L] += T[b,t,:] · kb[b,s,:]  (256x128 tiles, 2 blocks/CU)
  corr_gemm<<<512, 512, 0, stream>>>(T, kb, mv);

  topk_softmax<<<1, 1024, 0, stream>>>(mv, idx, w);

  // out[b,l,:] = sum_k w_k * U[b,(l+d_k)%L,:]
  gather_out<<<dim3(Ll / 4, Bb), 256, 0, stream>>>(U, w, idx, out);
}